// Round 6
// baseline (87.817 us; speedup 1.0000x reference)
//
#include <hip/hip_runtime.h>
#include <hip/hip_bf16.h>
#include <stdint.h>

typedef float  f32x4   __attribute__((ext_vector_type(4)));
typedef float  f32x16  __attribute__((ext_vector_type(16)));
typedef __bf16 bf16x8  __attribute__((ext_vector_type(8)));
typedef __bf16 bf16x4  __attribute__((ext_vector_type(4)));

static constexpr int NB = 8, NS = 1024, NE = 1024, NH = 16;

#define MFMA16(a, b, c) __builtin_amdgcn_mfma_f32_16x16x32_bf16((a), (b), (c), 0, 0, 0)
#define MFMA32(a, b, c) __builtin_amdgcn_mfma_f32_32x32x16_bf16((a), (b), (c), 0, 0, 0)

__device__ __forceinline__ void gload_lds16(const void* g, void* l) {
    __builtin_amdgcn_global_load_lds(
        (const __attribute__((address_space(1))) void*)g,
        (__attribute__((address_space(3))) void*)l, 16, 0, 0);
}

__device__ __forceinline__ uint32_t cvt_pk_bf16(float lo, float hi) {
    uint32_t r;
    asm("v_cvt_pk_bf16_f32 %0, %1, %2" : "=v"(r) : "v"(lo), "v"(hi));
    return r;
}
__device__ __forceinline__ void pl32swap(uint32_t& a, uint32_t& b) {
    asm volatile("v_permlane32_swap_b32 %0, %1" : "+v"(a), "+v"(b));
}
__device__ __forceinline__ float exp2_raw(float x) {
    float r;
    asm("v_exp_f32 %0, %1" : "=v"(r) : "v"(x));
    return r;
}

// ---------------------------------------------------------------------------
// Kernel 1: proj = cos(x + theta), dual layout.
// ---------------------------------------------------------------------------
__global__ __launch_bounds__(256) void k_proj(const float* __restrict__ x,
                                              const float* __restrict__ theta,
                                              __bf16* __restrict__ proj,
                                              __bf16* __restrict__ projT) {
    __shared__ float sm[64][65];
    const int bid  = blockIdx.x;
    const int bh   = bid >> 4;
    const int st0  = (bid & 15) << 6;
    const int b    = bh >> 4, h = bh & 15;
    const int t    = threadIdx.x;
    const int srow = t >> 2;
    const int j4   = t & 3;

    const float* xrow = x + ((size_t)(b * NS + st0 + srow)) * NE + h * 64;
    __bf16* prow = proj + ((size_t)bh * NS + st0 + srow) * 64;

#pragma unroll
    for (int k = 0; k < 4; ++k) {
        const int d = k * 16 + j4 * 4;
        float4 xv = *(const float4*)(xrow + d);
        float4 tv = *(const float4*)(theta + d);
        float c0 = __cosf(xv.x + tv.x);
        float c1 = __cosf(xv.y + tv.y);
        float c2 = __cosf(xv.z + tv.z);
        float c3 = __cosf(xv.w + tv.w);
        bf16x4 pv = {(__bf16)c0, (__bf16)c1, (__bf16)c2, (__bf16)c3};
        *(bf16x4*)(prow + d) = pv;
        sm[d + 0][srow] = c0;
        sm[d + 1][srow] = c1;
        sm[d + 2][srow] = c2;
        sm[d + 3][srow] = c3;
    }
    __syncthreads();

    const int drow = t >> 2;
    bf16x8 o0, o1;
#pragma unroll
    for (int i = 0; i < 8; ++i) {
        o0[i] = (__bf16)sm[drow][j4 * 16 + i];
        o1[i] = (__bf16)sm[drow][j4 * 16 + 8 + i];
    }
    __bf16* dst = projT + ((size_t)bh * 64 + drow) * NS + st0 + j4 * 16;
    *(bf16x8*)dst = o0;
    *(bf16x8*)(dst + 8) = o1;
}

// ---------------------------------------------------------------------------
// Kernel 2: W (f32 [E,E]) -> bf16
// ---------------------------------------------------------------------------
__global__ __launch_bounds__(256) void k_cvtW(const float* __restrict__ W,
                                              __bf16* __restrict__ Wb) {
    const int i = (blockIdx.x * 256 + threadIdx.x) * 4;
    float4 v = *(const float4*)(W + i);
    bf16x4 o = {(__bf16)v.x, (__bf16)v.y, (__bf16)v.z, (__bf16)v.w};
    *(bf16x4*)(Wb + i) = o;
}

// ---------------------------------------------------------------------------
// Kernel 3: flash attention, 32x32x16 MFMA, in-register softmax.
//   Grid 1024: 8 q-blocks per (b,h), 4 waves x 32 q-rows each -> 4 blocks/CU.
//   XCD-grouping decode: all 8 q-blocks of a (b,h) land on one XCD's L2.
//   Q recomputed from x in f32 and rounded ONCE after csc scaling (accuracy).
//   Fixed-shift-free softmax: scores already in exp2 domain, shift cancels.
// ---------------------------------------------------------------------------
__global__ __launch_bounds__(256, 4) void k_attn(const float* __restrict__ x,
                                                 const float* __restrict__ theta,
                                                 const __bf16* __restrict__ proj,
                                                 const __bf16* __restrict__ projT,
                                                 __bf16* __restrict__ attn_out) {
    __shared__ __align__(16) char smem[32768];
    __bf16* const smK0 = (__bf16*)(smem);
    __bf16* const smV0 = (__bf16*)(smem + 8192);
    __bf16* const smK1 = (__bf16*)(smem + 16384);
    __bf16* const smV1 = (__bf16*)(smem + 24576);

    const int bid  = blockIdx.x;        // 0..1023
    // XCD-grouping: xcd = bid&7; 16 bh's per XCD; qblk = slowest.
    const int bh   = (bid & 7) + 8 * ((bid >> 3) & 15);
    const int qblk = bid >> 7;          // 0..7
    const int t    = threadIdx.x;
    const int w    = t >> 6;
    const int lane = t & 63;
    const int hi   = lane >> 5;         // 0..1
    const int l5   = lane & 31;         // 0..31
    const int l7   = l5 & 7;
    const int qw   = qblk * 128 + w * 32;   // wave q-base (32 rows)
    const int b    = bh >> 4, h = bh & 15;

    const __bf16* P  = proj  + (size_t)bh * NS * 64;
    const __bf16* PT = projT + (size_t)bh * 64 * NS;

    const float csc = 0.18033688f;   // (1/sqrt(64)) * log2(e)

    // Q fragments (B operand), from x in f32, scaled THEN rounded once.
    bf16x8 bq[4];
    {
        const float* xr = x + ((size_t)(b * NS + qw + l5)) * NE + h * 64;
#pragma unroll
        for (int d = 0; d < 4; ++d) {
            const int d0 = d * 16 + hi * 8;
            float4 x0 = *(const float4*)(xr + d0);
            float4 x1 = *(const float4*)(xr + d0 + 4);
            float4 t0 = *(const float4*)(theta + d0);
            float4 t1 = *(const float4*)(theta + d0 + 4);
            bf16x8 o;
            o[0] = (__bf16)(__cosf(x0.x + t0.x) * csc);
            o[1] = (__bf16)(__cosf(x0.y + t0.y) * csc);
            o[2] = (__bf16)(__cosf(x0.z + t0.z) * csc);
            o[3] = (__bf16)(__cosf(x0.w + t0.w) * csc);
            o[4] = (__bf16)(__cosf(x1.x + t1.x) * csc);
            o[5] = (__bf16)(__cosf(x1.y + t1.y) * csc);
            o[6] = (__bf16)(__cosf(x1.z + t1.z) * csc);
            o[7] = (__bf16)(__cosf(x1.w + t1.w) * csc);
            bq[d] = o;
        }
    }

    // Hoisted swizzled LDS read bases (per-lane), both dbuf copies.
    const __bf16* kP0[4];
    const __bf16* kP1[4];
    const __bf16* vP0[4];
    const __bf16* vP1[4];
#pragma unroll
    for (int d = 0; d < 4; ++d) {
        const int off = l5 * 64 + ((d * 2 + hi) ^ l7) * 8;
        kP0[d] = smK0 + off;
        kP1[d] = smK1 + off;
        vP0[d] = smV0 + off;
        vP1[d] = smV1 + off;
    }

    // Staging geometry (linear LDS dest, pre-swizzled global source).
    const int srow  = t >> 3;
    const int sjsrc = (t & 7) ^ (srow & 7);
    char* const dK0 = (char*)smK0 + t * 16;
    char* const dV0 = (char*)smV0 + t * 16;
    char* const dK1 = (char*)smK1 + t * 16;
    char* const dV1 = (char*)smV1 + t * 16;

#define STAGE(kvoff, dk, dv)                                                           \
    do {                                                                               \
        gload_lds16(P  + (size_t)((kvoff) + srow)      * 64 + sjsrc * 8, (dk));        \
        gload_lds16(P  + (size_t)((kvoff) + 32 + srow) * 64 + sjsrc * 8, (dk) + 4096); \
        gload_lds16(PT + (size_t)srow        * NS + (kvoff) + sjsrc * 8, (dv));        \
        gload_lds16(PT + (size_t)(32 + srow) * NS + (kvoff) + sjsrc * 8, (dv) + 4096); \
    } while (0)

    f32x16 acc[2];
#pragma unroll
    for (int dt = 0; dt < 2; ++dt)
        acc[dt] = (f32x16){0.f,0.f,0.f,0.f,0.f,0.f,0.f,0.f,0.f,0.f,0.f,0.f,0.f,0.f,0.f,0.f};
    float rs = 0.f;

    auto compute = [&](const __bf16* const* kR, const __bf16* const* vR) {
#pragma unroll
        for (int kt = 0; kt < 2; ++kt) {
            bf16x8 ak[4];
#pragma unroll
            for (int d = 0; d < 4; ++d)
                ak[d] = *(const bf16x8*)(kR[d] + kt * 2048);

            f32x16 st = (f32x16){0.f,0.f,0.f,0.f,0.f,0.f,0.f,0.f,0.f,0.f,0.f,0.f,0.f,0.f,0.f,0.f};
            __builtin_amdgcn_s_setprio(1);
#pragma unroll
            for (int d = 0; d < 4; ++d) st = MFMA32(ak[d], bq[d], st);
            __builtin_amdgcn_s_setprio(0);

            float p[16];
#pragma unroll
            for (int r = 0; r < 16; ++r) p[r] = exp2_raw(st[r]);
            rs += (((p[0] + p[1]) + (p[2] + p[3])) + ((p[4] + p[5]) + (p[6] + p[7]))) +
                  (((p[8] + p[9]) + (p[10] + p[11])) + ((p[12] + p[13]) + (p[14] + p[15])));
            uint32_t c0[8];
#pragma unroll
            for (int j = 0; j < 8; ++j) c0[j] = cvt_pk_bf16(p[2 * j], p[2 * j + 1]);
            pl32swap(c0[0], c0[2]); pl32swap(c0[1], c0[3]);
            pl32swap(c0[4], c0[6]); pl32swap(c0[5], c0[7]);

#pragma unroll
            for (int half = 0; half < 2; ++half) {
                const int ks = kt * 2 + half;
                union U4 { uint32_t u[4]; bf16x8 v; } f0;
#pragma unroll
                for (int j = 0; j < 4; ++j) f0.u[j] = c0[half * 4 + j];
                __builtin_amdgcn_s_setprio(1);
#pragma unroll
                for (int dt = 0; dt < 2; ++dt) {
                    bf16x8 av = *(const bf16x8*)(vR[ks] + dt * 2048);
                    acc[dt] = MFMA32(av, f0.v, acc[dt]);
                }
                __builtin_amdgcn_s_setprio(0);
            }
        }
    };

    STAGE(0, dK0, dV0);
    __syncthreads();

#pragma unroll 1
    for (int it2 = 0; it2 < 8; ++it2) {
        STAGE((2 * it2 + 1) * 64, dK1, dV1);
        compute(kP0, vP0);
        __syncthreads();
        if (it2 < 7) STAGE((2 * it2 + 2) * 64, dK0, dV0);
        compute(kP1, vP1);
        __syncthreads();
    }
#undef STAGE

    // Epilogue: wave-private LDS transpose.
    float* const epw = (float*)smem + w * (32 * 33);
    const int orow = lane >> 1;
    const int ohalf = lane & 1;

    rs += __shfl_xor(rs, 32);
    const float inv = 1.0f / rs;
#pragma unroll
    for (int dt = 0; dt < 2; ++dt) {
        const f32x16 a = acc[dt];
#pragma unroll
        for (int r = 0; r < 16; ++r)
            epw[l5 * 33 + (r & 3) + 8 * (r >> 2) + 4 * hi] = a[r] * inv;
        bf16x8 o0, o1;
#pragma unroll
        for (int i = 0; i < 8; ++i) {
            o0[i] = (__bf16)(epw[orow * 33 + ohalf * 16 + i]);
            o1[i] = (__bf16)(epw[orow * 33 + ohalf * 16 + 8 + i]);
        }
        __bf16* dst = attn_out +
            ((size_t)b * NS + qblk * 128 + w * 32 + orow) * NE +
            h * 64 + dt * 32 + ohalf * 16;
        *(bf16x8*)dst = o0;
        *(bf16x8*)(dst + 8) = o1;
    }
}

// ---------------------------------------------------------------------------
// Kernel 4: C[M,N] = A[M,K](bf16) x W^T   (m97 structure, 128x128, BK=32)
// ---------------------------------------------------------------------------
__global__ __launch_bounds__(256) void k_gemm(const __bf16* __restrict__ A,
                                              const __bf16* __restrict__ Bw,
                                              float* __restrict__ C) {
    constexpr int K = 1024, N = 1024;
    __shared__ __bf16 As[128 * 32];
    __shared__ __bf16 Bs[128 * 32];

    const int t = threadIdx.x;
    const int lane = t & 63, w = t >> 6;
    const int g = lane >> 4, c = lane & 15;
    const int wr = w >> 1, wc = w & 1;
    const size_t row0 = (size_t)blockIdx.x * 128;
    const size_t col0 = (size_t)blockIdx.y * 128;

    const char* Ag = (const char*)(A + row0 * K);
    const char* Bg = (const char*)(Bw + col0 * K);
    char* AsB = (char*)As;
    char* BsB = (char*)Bs;
    const int srow  = t >> 2;
    const int sbyte = (t & 3) * 16;

    f32x4 acc[4][4];
#pragma unroll
    for (int m = 0; m < 4; ++m)
#pragma unroll
        for (int n = 0; n < 4; ++n) acc[m][n] = (f32x4){0.f, 0.f, 0.f, 0.f};

    for (int kb = 0; kb < K; kb += 32) {
        gload_lds16(Ag + (size_t)srow * (K * 2) + kb * 2 + sbyte, AsB + t * 16);
        gload_lds16(Ag + (size_t)(srow + 64) * (K * 2) + kb * 2 + sbyte, AsB + 4096 + t * 16);
        gload_lds16(Bg + (size_t)srow * (K * 2) + kb * 2 + sbyte, BsB + t * 16);
        gload_lds16(Bg + (size_t)(srow + 64) * (K * 2) + kb * 2 + sbyte, BsB + 4096 + t * 16);
        __syncthreads();

        bf16x8 a[4], b[4];
#pragma unroll
        for (int m = 0; m < 4; ++m)
            a[m] = *(const bf16x8*)(As + (wr * 64 + m * 16 + c) * 32 + g * 8);
#pragma unroll
        for (int n = 0; n < 4; ++n)
            b[n] = *(const bf16x8*)(Bs + (wc * 64 + n * 16 + c) * 32 + g * 8);
#pragma unroll
        for (int m = 0; m < 4; ++m)
#pragma unroll
            for (int n = 0; n < 4; ++n) acc[m][n] = MFMA16(a[m], b[n], acc[m][n]);
        __syncthreads();
    }

#pragma unroll
    for (int m = 0; m < 4; ++m)
#pragma unroll
        for (int n = 0; n < 4; ++n)
#pragma unroll
            for (int r = 0; r < 4; ++r)
                C[(row0 + wr * 64 + m * 16 + 4 * g + r) * N + col0 + wc * 64 + n * 16 + c] =
                    acc[m][n][r];
}

// ---------------------------------------------------------------------------
extern "C" void kernel_launch(void* const* d_in, const int* in_sizes, int n_in,
                              void* d_out, int out_size, void* d_ws, size_t ws_size,
                              hipStream_t stream) {
    const float* x     = (const float*)d_in[0];
    const float* theta = (const float*)d_in[1];
    const float* W     = (const float*)d_in[2];
    float* out = (float*)d_out;

    char* ws = (char*)d_ws;
    __bf16* proj  = (__bf16*)(ws);
    __bf16* projT = (__bf16*)(ws + 16777216);
    __bf16* Wb    = (__bf16*)(ws + 33554432);
    __bf16* ao    = (__bf16*)(ws + 35651584);

    k_proj<<<NB * NH * (NS / 64), 256, 0, stream>>>(x, theta, proj, projT);
    k_cvtW<<<(NE * NE / 4) / 256, 256, 0, stream>>>(W, Wb);
    k_attn<<<NB * NH * 8, 256, 0, stream>>>(x, theta, proj, projT, ao);
    dim3 gg(NB * NS / 128, NE / 128);
    k_gemm<<<gg, 256, 0, stream>>>(ao, Wb, out);
}